// Round 2
// baseline (1371.643 us; speedup 1.0000x reference)
//
#include <hip/hip_runtime.h>

#define S_LEN 2048
#define NH 16
#define HD 64
#define NBH 32   // B*H
#define TOPK 256

// ---------------------------------------------------------------------------
// Generic fp32 GEMM: C = alpha * (A @ B^T) + bias
//   A: M x K row-major (lda = K);  B: N x K row-major (ldb = K)
//   mode 0: C[m*ldc + n]
//   mode 1: QKV head layout: C[((b*NH + h)*S + s)*D + d], m=b*S+s, n=h*D+d
// 64x64 tile, 256 threads, 4x4 micro-tile per thread, KT=16.
// LDS tiles stored transposed [k][m] so fragment reads are ds_read_b128.
// ---------------------------------------------------------------------------
__global__ __launch_bounds__(256)
void gemm_abt(const float* __restrict__ A, const float* __restrict__ B,
              const float* __restrict__ bias, float* __restrict__ C,
              int M, int N, int K, float alpha, int mode, int ldc,
              size_t aStrideZ, size_t bStrideZ, size_t cStrideZ)
{
    A += blockIdx.z * aStrideZ;
    B += blockIdx.z * bStrideZ;
    C += blockIdx.z * cStrideZ;

    __shared__ float As[16][68];   // [k][m]; stride 68 -> 16B aligned, 2-way banks
    __shared__ float Bs[16][68];   // [k][n]

    const int tid  = threadIdx.x;
    const int tx   = tid & 15;     // n-direction
    const int ty   = tid >> 4;     // m-direction
    const int m0   = blockIdx.y * 64;
    const int n0   = blockIdx.x * 64;
    const int lrow = tid >> 2;        // 0..63 tile row for staging loads
    const int lk4  = (tid & 3) * 4;   // k offset 0,4,8,12

    float acc[4][4] = {};

    for (int k0 = 0; k0 < K; k0 += 16) {
        const float4 a4 = *reinterpret_cast<const float4*>(&A[(size_t)(m0 + lrow) * K + k0 + lk4]);
        const float4 b4 = *reinterpret_cast<const float4*>(&B[(size_t)(n0 + lrow) * K + k0 + lk4]);
        __syncthreads();   // previous iteration's reads done before overwrite
        As[lk4 + 0][lrow] = a4.x; As[lk4 + 1][lrow] = a4.y;
        As[lk4 + 2][lrow] = a4.z; As[lk4 + 3][lrow] = a4.w;
        Bs[lk4 + 0][lrow] = b4.x; Bs[lk4 + 1][lrow] = b4.y;
        Bs[lk4 + 2][lrow] = b4.z; Bs[lk4 + 3][lrow] = b4.w;
        __syncthreads();
        #pragma unroll
        for (int kk = 0; kk < 16; ++kk) {
            const float4 av = *reinterpret_cast<const float4*>(&As[kk][ty * 4]);
            const float4 bv = *reinterpret_cast<const float4*>(&Bs[kk][tx * 4]);
            const float a[4] = {av.x, av.y, av.z, av.w};
            const float b[4] = {bv.x, bv.y, bv.z, bv.w};
            #pragma unroll
            for (int i = 0; i < 4; ++i)
                #pragma unroll
                for (int j = 0; j < 4; ++j)
                    acc[i][j] = fmaf(a[i], b[j], acc[i][j]);
        }
    }

    float4 bias4 = make_float4(0.f, 0.f, 0.f, 0.f);
    if (bias) bias4 = *reinterpret_cast<const float4*>(&bias[n0 + tx * 4]);

    #pragma unroll
    for (int i = 0; i < 4; ++i) {
        const int m = m0 + ty * 4 + i;
        float4 r;
        r.x = acc[i][0] * alpha + bias4.x;
        r.y = acc[i][1] * alpha + bias4.y;
        r.z = acc[i][2] * alpha + bias4.z;
        r.w = acc[i][3] * alpha + bias4.w;
        if (mode == 0) {
            *reinterpret_cast<float4*>(&C[(size_t)m * ldc + n0 + tx * 4]) = r;
        } else {
            const int b = m >> 11, s = m & (S_LEN - 1);
            const int h = n0 >> 6, d = tx * 4;
            *reinterpret_cast<float4*>(&C[(((size_t)(b * NH + h)) * S_LEN + s) * HD + d]) = r;
        }
    }
}

// ---------------------------------------------------------------------------
// Per-row exact top-k(256) + softmax + sparse PV.
// One wave (64 lanes) per query row; 4 waves per block.
// Row's 2048 scores live in registers: 32 per lane, t = c*256 + lane*4 + i
// (all statically indexed). Bit-exact binary search on sortable-uint keys;
// ties broken by lowest t (matches jax.lax.top_k / reference semantics).
// ---------------------------------------------------------------------------
__device__ __forceinline__ float wredf_max(float v) {
    #pragma unroll
    for (int m = 32; m > 0; m >>= 1) v = fmaxf(v, __shfl_xor(v, m, 64));
    return v;
}
__device__ __forceinline__ float wredf_add(float v) {
    #pragma unroll
    for (int m = 32; m > 0; m >>= 1) v += __shfl_xor(v, m, 64);
    return v;
}
__device__ __forceinline__ int wredi_add(int v) {
    #pragma unroll
    for (int m = 32; m > 0; m >>= 1) v += __shfl_xor(v, m, 64);
    return v;
}

__global__ __launch_bounds__(256)
void topk_softmax_pv(const float* __restrict__ scores, const float* __restrict__ V,
                     float* __restrict__ att, int bh0)
{
    const int wave = threadIdx.x >> 6;
    const int lane = threadIdx.x & 63;
    const int bh   = bh0 + blockIdx.y;
    const int row  = blockIdx.x * 4 + wave;

    const float* srow = scores + (size_t)blockIdx.y * S_LEN * S_LEN + (size_t)row * S_LEN;

    // ---- load 32 scores per lane (coalesced float4) ----
    float s[32];
    #pragma unroll
    for (int c = 0; c < 8; ++c) {
        const float4 v4 = *reinterpret_cast<const float4*>(&srow[c * 256 + lane * 4]);
        s[c * 4 + 0] = v4.x; s[c * 4 + 1] = v4.y;
        s[c * 4 + 2] = v4.z; s[c * 4 + 3] = v4.w;
    }

    // ---- row max ----
    float mx = s[0];
    #pragma unroll
    for (int i = 1; i < 32; ++i) mx = fmaxf(mx, s[i]);
    mx = wredf_max(mx);

    // ---- sortable-uint keys ----
    unsigned u[32];
    #pragma unroll
    for (int i = 0; i < 32; ++i) {
        const unsigned b = __float_as_uint(s[i]);
        u[i] = (b & 0x80000000u) ? ~b : (b | 0x80000000u);
    }

    // ---- bit-exact binary search for tau = 256th-largest key ----
    unsigned tau = 0u;
    for (int bit = 31; bit >= 0; --bit) {        // runtime loop, static body
        const unsigned cand = tau | (1u << bit);
        int cnt = 0;
        #pragma unroll
        for (int i = 0; i < 32; ++i) cnt += (u[i] >= cand) ? 1 : 0;
        cnt = wredi_add(cnt);
        if (cnt >= TOPK) tau = cand;
    }

    int cg = 0;
    #pragma unroll
    for (int i = 0; i < 32; ++i) cg += (u[i] > tau) ? 1 : 0;
    cg = wredi_add(cg);
    const int quota = TOPK - cg;   // in [1,256]

    // ---- include flags (ties by ascending t) -> w = exp(s-mx) in place ----
    const unsigned long long below = (1ull << lane) - 1ull;
    int prev = 0;
    #pragma unroll
    for (int c = 0; c < 8; ++c) {
        unsigned long long bl[4];
        #pragma unroll
        for (int i = 0; i < 4; ++i) bl[i] = __ballot(u[c * 4 + i] == tau);
        const int below_all = __popcll(bl[0] & below) + __popcll(bl[1] & below)
                            + __popcll(bl[2] & below) + __popcll(bl[3] & below);
        int own = 0;
        #pragma unroll
        for (int i = 0; i < 4; ++i) {
            const bool tie = (u[c * 4 + i] == tau);
            const bool inc = (u[c * 4 + i] > tau) ||
                             (tie && (prev + below_all + own) < quota);
            own += tie ? 1 : 0;
            s[c * 4 + i] = inc ? __expf(s[c * 4 + i] - mx) : 0.0f;
        }
        prev += __popcll(bl[0]) + __popcll(bl[1]) + __popcll(bl[2]) + __popcll(bl[3]);
    }

    float ds = 0.f;
    #pragma unroll
    for (int i = 0; i < 32; ++i) ds += s[i];
    const float inv = 1.0f / wredf_add(ds);   // max element always included -> >=1

    // ---- compact included (t,w) pairs to LDS (exactly <=256 per row) ----
    __shared__ unsigned lt[4][TOPK];
    __shared__ float    lw[4][TOPK];
    int base = 0;
    #pragma unroll
    for (int c = 0; c < 8; ++c) {
        #pragma unroll
        for (int i = 0; i < 4; ++i) {
            const bool inc = (s[c * 4 + i] != 0.0f);
            const unsigned long long b = __ballot(inc);
            if (inc) {
                const int pos = base + __popcll(b & below);
                lt[wave][pos] = (unsigned)(c * 256 + lane * 4 + i);
                lw[wave][pos] = s[c * 4 + i];
            }
            base += __popcll(b);
        }
    }

    // ---- sparse PV: lane <-> d, gather ~256 V rows (coalesced 256B each) ----
    const float* vh = V + (size_t)bh * S_LEN * HD;
    float out = 0.f;
    for (int idx = 0; idx < base; ++idx) {
        const unsigned t = lt[wave][idx];
        const float   wt = lw[wave][idx];
        out = fmaf(wt, vh[(size_t)t * HD + lane], out);
    }

    // att layout (B,S,H,D) == (B,S,E) row-major
    const int b = bh >> 4, h = bh & 15;
    att[(((size_t)b * S_LEN + row) * NH + h) * HD + lane] = out * inv;
}

// ---------------------------------------------------------------------------
extern "C" void kernel_launch(void* const* d_in, const int* in_sizes, int n_in,
                              void* d_out, int out_size, void* d_ws, size_t ws_size,
                              hipStream_t stream)
{
    const float* x  = (const float*)d_in[0];
    const float* Wq = (const float*)d_in[1];
    const float* bq = (const float*)d_in[2];
    const float* Wk = (const float*)d_in[3];
    const float* bk = (const float*)d_in[4];
    const float* Wv = (const float*)d_in[5];
    const float* bv = (const float*)d_in[6];
    const float* Wo = (const float*)d_in[7];
    const float* bo = (const float*)d_in[8];
    float* out = (float*)d_out;

    const size_t SD       = (size_t)S_LEN * HD;        // 131072 elems per head
    const size_t qkvElems = (size_t)NBH * SD;          // 4.19M elems (16 MB)
    float* q_ws = (float*)d_ws;
    float* k_ws = q_ws + qkvElems;
    float* v_ws = k_ws + qkvElems;
    float* attb = v_ws + qkvElems;
    float* sc   = attb + qkvElems;                     // score scratch (chunked)

    const size_t scorePerHead = (size_t)S_LEN * S_LEN; // 4.19M elems (16 MB)
    const size_t fixedBytes   = 4 * qkvElems * sizeof(float); // 64 MB
    size_t availHeads = 0;
    if (ws_size > fixedBytes)
        availHeads = (ws_size - fixedBytes) / (scorePerHead * sizeof(float));
    int hc = (int)(availHeads < 1 ? 1 : (availHeads > (size_t)NBH ? (size_t)NBH : availHeads));

    const dim3 blk(256);

    // QKV projections: (4096x1024) @ (1024x1024)^T + bias -> (B,H,S,D)
    gemm_abt<<<dim3(16, 64, 1), blk, 0, stream>>>(x, Wq, bq, q_ws, 4096, 1024, 1024, 1.f, 1, 0, 0, 0, 0);
    gemm_abt<<<dim3(16, 64, 1), blk, 0, stream>>>(x, Wk, bk, k_ws, 4096, 1024, 1024, 1.f, 1, 0, 0, 0, 0);
    gemm_abt<<<dim3(16, 64, 1), blk, 0, stream>>>(x, Wv, bv, v_ws, 4096, 1024, 1024, 1.f, 1, 0, 0, 0, 0);

    // scores + topk/softmax/PV, chunked over heads to fit workspace
    for (int bh0 = 0; bh0 < NBH; bh0 += hc) {
        const int h = (bh0 + hc <= NBH) ? hc : (NBH - bh0);
        gemm_abt<<<dim3(32, 32, h), blk, 0, stream>>>(
            q_ws + (size_t)bh0 * SD, k_ws + (size_t)bh0 * SD, nullptr, sc,
            2048, 2048, 64, 0.125f, 0, 2048, SD, SD, scorePerHead);
        topk_softmax_pv<<<dim3(512, h), blk, 0, stream>>>(sc, v_ws, attb, bh0);
    }

    // output projection: (4096x1024) @ Wo^T + bo -> d_out
    gemm_abt<<<dim3(16, 64, 1), blk, 0, stream>>>(attb, Wo, bo, out, 4096, 1024, 1024, 1.f, 0, 1024, 0, 0, 0);
}

// Round 3
// 1275.803 us; speedup vs baseline: 1.0751x; 1.0751x over previous
//
#include <hip/hip_runtime.h>

#define S_LEN 2048
#define NH 16
#define HD 64
#define NBH 32   // B*H
#define TOPK 256

// ---------------------------------------------------------------------------
// Generic fp32 GEMM: C = alpha * (A @ B^T) + bias
//   A: M x K row-major (lda = K);  B: N x K row-major (ldb = K)
//   mode 0: C[m*ldc + n]
//   mode 1: QKV head layout: C[((b*NH + h)*S + s)*D + d], m=b*S+s, n=h*D+d
// 64x64 tile, 256 threads, 4x4 micro-tile per thread, KT=16.
// ---------------------------------------------------------------------------
__global__ __launch_bounds__(256)
void gemm_abt(const float* __restrict__ A, const float* __restrict__ B,
              const float* __restrict__ bias, float* __restrict__ C,
              int M, int N, int K, float alpha, int mode, int ldc,
              size_t aStrideZ, size_t bStrideZ, size_t cStrideZ)
{
    A += blockIdx.z * aStrideZ;
    B += blockIdx.z * bStrideZ;
    C += blockIdx.z * cStrideZ;

    __shared__ float As[16][68];   // [k][m]
    __shared__ float Bs[16][68];   // [k][n]

    const int tid  = threadIdx.x;
    const int tx   = tid & 15;     // n-direction
    const int ty   = tid >> 4;     // m-direction
    const int m0   = blockIdx.y * 64;
    const int n0   = blockIdx.x * 64;
    const int lrow = tid >> 2;
    const int lk4  = (tid & 3) * 4;

    float acc[4][4] = {};

    for (int k0 = 0; k0 < K; k0 += 16) {
        const float4 a4 = *reinterpret_cast<const float4*>(&A[(size_t)(m0 + lrow) * K + k0 + lk4]);
        const float4 b4 = *reinterpret_cast<const float4*>(&B[(size_t)(n0 + lrow) * K + k0 + lk4]);
        __syncthreads();
        As[lk4 + 0][lrow] = a4.x; As[lk4 + 1][lrow] = a4.y;
        As[lk4 + 2][lrow] = a4.z; As[lk4 + 3][lrow] = a4.w;
        Bs[lk4 + 0][lrow] = b4.x; Bs[lk4 + 1][lrow] = b4.y;
        Bs[lk4 + 2][lrow] = b4.z; Bs[lk4 + 3][lrow] = b4.w;
        __syncthreads();
        #pragma unroll
        for (int kk = 0; kk < 16; ++kk) {
            const float4 av = *reinterpret_cast<const float4*>(&As[kk][ty * 4]);
            const float4 bv = *reinterpret_cast<const float4*>(&Bs[kk][tx * 4]);
            const float a[4] = {av.x, av.y, av.z, av.w};
            const float b[4] = {bv.x, bv.y, bv.z, bv.w};
            #pragma unroll
            for (int i = 0; i < 4; ++i)
                #pragma unroll
                for (int j = 0; j < 4; ++j)
                    acc[i][j] = fmaf(a[i], b[j], acc[i][j]);
        }
    }

    float4 bias4 = make_float4(0.f, 0.f, 0.f, 0.f);
    if (bias) bias4 = *reinterpret_cast<const float4*>(&bias[n0 + tx * 4]);

    #pragma unroll
    for (int i = 0; i < 4; ++i) {
        const int m = m0 + ty * 4 + i;
        float4 r;
        r.x = acc[i][0] * alpha + bias4.x;
        r.y = acc[i][1] * alpha + bias4.y;
        r.z = acc[i][2] * alpha + bias4.z;
        r.w = acc[i][3] * alpha + bias4.w;
        if (mode == 0) {
            *reinterpret_cast<float4*>(&C[(size_t)m * ldc + n0 + tx * 4]) = r;
        } else {
            const int b = m >> 11, s = m & (S_LEN - 1);
            const int h = n0 >> 6, d = tx * 4;
            *reinterpret_cast<float4*>(&C[(((size_t)(b * NH + h)) * S_LEN + s) * HD + d]) = r;
        }
    }
}

// ---------------------------------------------------------------------------
// Per-row exact top-k(256) + softmax + sparse PV.
// One wave per query row; 4 waves per block.
// Selection: LDS radix-256 select (4 rounds x 8 bits, MSB-first) on
// sortable-uint keys -> exact 32-bit tau + tie quota. Ties broken by lowest
// t (matches jax.lax.top_k). Fast path when no cross-value ties at tau.
// ---------------------------------------------------------------------------
__device__ __forceinline__ float wredf_max(float v) {
    #pragma unroll
    for (int m = 32; m > 0; m >>= 1) v = fmaxf(v, __shfl_xor(v, m, 64));
    return v;
}
__device__ __forceinline__ float wredf_add(float v) {
    #pragma unroll
    for (int m = 32; m > 0; m >>= 1) v += __shfl_xor(v, m, 64);
    return v;
}

__global__ __launch_bounds__(256)
void topk_softmax_pv(const float* __restrict__ scores, const float* __restrict__ V,
                     float* __restrict__ att, int bh0)
{
    const int wave = threadIdx.x >> 6;
    const int lane = threadIdx.x & 63;
    const int bh   = bh0 + blockIdx.y;
    const int row  = blockIdx.x * 4 + wave;

    const float* srow = scores + (size_t)blockIdx.y * S_LEN * S_LEN + (size_t)row * S_LEN;

    // ---- load 32 scores per lane (t = c*256 + lane*4 + i) ----
    float s[32];
    #pragma unroll
    for (int c = 0; c < 8; ++c) {
        const float4 v4 = *reinterpret_cast<const float4*>(&srow[c * 256 + lane * 4]);
        s[c * 4 + 0] = v4.x; s[c * 4 + 1] = v4.y;
        s[c * 4 + 2] = v4.z; s[c * 4 + 3] = v4.w;
    }

    // ---- row max ----
    float mx = s[0];
    #pragma unroll
    for (int i = 1; i < 32; ++i) mx = fmaxf(mx, s[i]);
    mx = wredf_max(mx);

    // ---- sortable-uint keys ----
    unsigned u[32];
    #pragma unroll
    for (int i = 0; i < 32; ++i) {
        const unsigned b = __float_as_uint(s[i]);
        u[i] = (b & 0x80000000u) ? ~b : (b | 0x80000000u);
    }

    // ---- radix-256 select: exact tau (32-bit) + quota ----
    __shared__ unsigned hist[4][256];
    unsigned prefix = 0;
    int kRem = TOPK;
    unsigned count_eq = 0;

    #pragma unroll
    for (int r = 0; r < 4; ++r) {
        *reinterpret_cast<uint4*>(&hist[wave][lane * 4]) = make_uint4(0u, 0u, 0u, 0u);
        __syncthreads();
        const int sh = 24 - 8 * r;
        #pragma unroll
        for (int i = 0; i < 32; ++i) {
            const unsigned dig = (u[i] >> sh) & 0xFFu;
            unsigned add = 1u;
            if (r > 0) add = ((u[i] >> (32 - 8 * r)) == prefix) ? 1u : 0u;
            atomicAdd(&hist[wave][dig], add);   // add of 0 for inactive: branchless
        }
        __syncthreads();
        const uint4 bv = *reinterpret_cast<const uint4*>(&hist[wave][lane * 4]);
        const unsigned cnt = bv.x + bv.y + bv.z + bv.w;
        unsigned sfx = cnt;                      // inclusive suffix-sum over lanes
        #pragma unroll
        for (int dd = 1; dd < 64; dd <<= 1) {
            const unsigned t = __shfl_down(sfx, dd, 64);
            if (lane + dd < 64) sfx += t;
        }
        const unsigned g3 = sfx - cnt;           // #elems with digit > 4*lane+3
        const unsigned g2 = g3 + bv.w;
        const unsigned g1 = g2 + bv.z;
        const unsigned g0 = g1 + bv.y;
        const unsigned kr = (unsigned)kRem;
        int myd = -1; unsigned mygt = 0, myc = 0;
        if      (g3 < kr && g3 + bv.w >= kr) { myd = 4*lane+3; mygt = g3; myc = bv.w; }
        else if (g2 < kr && g2 + bv.z >= kr) { myd = 4*lane+2; mygt = g2; myc = bv.z; }
        else if (g1 < kr && g1 + bv.y >= kr) { myd = 4*lane+1; mygt = g1; myc = bv.y; }
        else if (g0 < kr && g0 + bv.x >= kr) { myd = 4*lane+0; mygt = g0; myc = bv.x; }
        const unsigned long long bal = __ballot(myd >= 0);
        const int src = __ffsll((unsigned long long)bal) - 1;
        const int d   = __shfl(myd, src, 64);
        kRem    -= __shfl((int)mygt, src, 64);
        count_eq = (unsigned)__shfl((int)myc, src, 64);
        prefix = (prefix << 8) | (unsigned)d;
    }
    const unsigned tau = prefix;     // exact key of the 256th largest
    const int quota = kRem;          // how many ==tau to take (lowest index first)

    // ---- inclusion bitmask ----
    const unsigned long long below = (1ull << lane) - 1ull;
    unsigned incbits = 0u;
    if ((unsigned)quota == count_eq) {
        // fast path: all ties included
        #pragma unroll
        for (int i = 0; i < 32; ++i)
            if (u[i] >= tau) incbits |= (1u << i);
    } else {
        int prev = 0;
        #pragma unroll
        for (int c = 0; c < 8; ++c) {
            unsigned long long bl[4];
            #pragma unroll
            for (int i = 0; i < 4; ++i) bl[i] = __ballot(u[c * 4 + i] == tau);
            const int below_all = __popcll(bl[0] & below) + __popcll(bl[1] & below)
                                + __popcll(bl[2] & below) + __popcll(bl[3] & below);
            int own = 0;
            #pragma unroll
            for (int i = 0; i < 4; ++i) {
                const bool tie = (u[c * 4 + i] == tau);
                const bool inc = (u[c * 4 + i] > tau) ||
                                 (tie && (prev + below_all + own) < quota);
                own += tie ? 1 : 0;
                if (inc) incbits |= (1u << (c * 4 + i));
            }
            prev += __popcll(bl[0]) + __popcll(bl[1]) + __popcll(bl[2]) + __popcll(bl[3]);
        }
    }

    // ---- exp + denominator ----
    float ds = 0.f;
    #pragma unroll
    for (int i = 0; i < 32; ++i) {
        const float w = ((incbits >> i) & 1u) ? __expf(s[i] - mx) : 0.0f;
        s[i] = w;
        ds += w;
    }
    const float inv = 1.0f / wredf_add(ds);

    // ---- compact exactly 256 (w,t) pairs to LDS (packed u64) ----
    __shared__ unsigned long long ltw[4][TOPK];
    int base = 0;
    #pragma unroll
    for (int c = 0; c < 8; ++c) {
        #pragma unroll
        for (int i = 0; i < 4; ++i) {
            const bool inc = ((incbits >> (c * 4 + i)) & 1u) != 0u;
            const unsigned long long b = __ballot(inc);
            if (inc) {
                const int pos = base + __popcll(b & below);
                ltw[wave][pos] = ((unsigned long long)__float_as_uint(s[c * 4 + i]) << 32)
                               | (unsigned)(c * 256 + lane * 4 + i);
            }
            base += __popcll(b);
        }
    }

    // ---- sparse PV: lane <-> d, 256 coalesced 256B gathers, 4 accumulators ----
    const float* vh = V + (size_t)bh * S_LEN * HD;
    float a0 = 0.f, a1 = 0.f, a2 = 0.f, a3 = 0.f;
    for (int idx = 0; idx < TOPK; idx += 4) {
        const unsigned long long e0 = ltw[wave][idx + 0];
        const unsigned long long e1 = ltw[wave][idx + 1];
        const unsigned long long e2 = ltw[wave][idx + 2];
        const unsigned long long e3 = ltw[wave][idx + 3];
        a0 = fmaf(__uint_as_float((unsigned)(e0 >> 32)), vh[(((unsigned)e0) << 6) + lane], a0);
        a1 = fmaf(__uint_as_float((unsigned)(e1 >> 32)), vh[(((unsigned)e1) << 6) + lane], a1);
        a2 = fmaf(__uint_as_float((unsigned)(e2 >> 32)), vh[(((unsigned)e2) << 6) + lane], a2);
        a3 = fmaf(__uint_as_float((unsigned)(e3 >> 32)), vh[(((unsigned)e3) << 6) + lane], a3);
    }

    const int b = bh >> 4, h = bh & 15;
    att[(((size_t)b * S_LEN + row) * NH + h) * HD + lane] = ((a0 + a1) + (a2 + a3)) * inv;
}

// ---------------------------------------------------------------------------
extern "C" void kernel_launch(void* const* d_in, const int* in_sizes, int n_in,
                              void* d_out, int out_size, void* d_ws, size_t ws_size,
                              hipStream_t stream)
{
    const float* x  = (const float*)d_in[0];
    const float* Wq = (const float*)d_in[1];
    const float* bq = (const float*)d_in[2];
    const float* Wk = (const float*)d_in[3];
    const float* bk = (const float*)d_in[4];
    const float* Wv = (const float*)d_in[5];
    const float* bv = (const float*)d_in[6];
    const float* Wo = (const float*)d_in[7];
    const float* bo = (const float*)d_in[8];
    float* out = (float*)d_out;

    const size_t SD       = (size_t)S_LEN * HD;
    const size_t qkvElems = (size_t)NBH * SD;
    float* q_ws = (float*)d_ws;
    float* k_ws = q_ws + qkvElems;
    float* v_ws = k_ws + qkvElems;
    float* attb = v_ws + qkvElems;
    float* sc   = attb + qkvElems;

    const size_t scorePerHead = (size_t)S_LEN * S_LEN;
    const size_t fixedBytes   = 4 * qkvElems * sizeof(float);
    size_t availHeads = 0;
    if (ws_size > fixedBytes)
        availHeads = (ws_size - fixedBytes) / (scorePerHead * sizeof(float));
    int hc = (int)(availHeads < 1 ? 1 : (availHeads > (size_t)NBH ? (size_t)NBH : availHeads));

    const dim3 blk(256);

    gemm_abt<<<dim3(16, 64, 1), blk, 0, stream>>>(x, Wq, bq, q_ws, 4096, 1024, 1024, 1.f, 1, 0, 0, 0, 0);
    gemm_abt<<<dim3(16, 64, 1), blk, 0, stream>>>(x, Wk, bk, k_ws, 4096, 1024, 1024, 1.f, 1, 0, 0, 0, 0);
    gemm_abt<<<dim3(16, 64, 1), blk, 0, stream>>>(x, Wv, bv, v_ws, 4096, 1024, 1024, 1.f, 1, 0, 0, 0, 0);

    for (int bh0 = 0; bh0 < NBH; bh0 += hc) {
        const int h = (bh0 + hc <= NBH) ? hc : (NBH - bh0);
        gemm_abt<<<dim3(32, 32, h), blk, 0, stream>>>(
            q_ws + (size_t)bh0 * SD, k_ws + (size_t)bh0 * SD, nullptr, sc,
            2048, 2048, 64, 0.125f, 0, 2048, SD, SD, scorePerHead);
        topk_softmax_pv<<<dim3(512, h), blk, 0, stream>>>(sc, v_ws, attb, bh0);
    }

    gemm_abt<<<dim3(16, 64, 1), blk, 0, stream>>>(attb, Wo, bo, out, 4096, 1024, 1024, 1.f, 0, 1024, 0, 0, 0);
}